// Round 2
// baseline (377.151 us; speedup 1.0000x reference)
//
#include <hip/hip_runtime.h>
#include <hip/hip_bf16.h>

typedef float f32x4 __attribute__((ext_vector_type(4)));
typedef __bf16 bf16x8 __attribute__((ext_vector_type(8)));

#define NB 4        // batch
#define NQ 4096
#define NK 4096
#define DIM 512
#define KD 64

__device__ inline bf16x8 load_cvt8(const float* __restrict__ p) {
    float4 f0 = *(const float4*)p;
    float4 f1 = *(const float4*)(p + 4);
    bf16x8 r;
    r[0] = (__bf16)f0.x; r[1] = (__bf16)f0.y; r[2] = (__bf16)f0.z; r[3] = (__bf16)f0.w;
    r[4] = (__bf16)f1.x; r[5] = (__bf16)f1.y; r[6] = (__bf16)f1.z; r[7] = (__bf16)f1.w;
    return r;
}

// ---- fused Q + K/V projection, 16 rows/wave, K-split 2, LDS f32 reduce.
// blocks 0..511: Q rows (32/block). blocks 512..1023: K/V rows (32/block).
__global__ __launch_bounds__(256, 4) void proj_kernel(
        const float* __restrict__ x, const float* __restrict__ buf,
        const float* __restrict__ Wq, const float* __restrict__ bq,
        const float* __restrict__ Wk, const float* __restrict__ bk,
        const float* __restrict__ Wv, const float* __restrict__ bv,
        __bf16* __restrict__ Qb, __bf16* __restrict__ Kb, __bf16* __restrict__ Vt) {
    __shared__ __align__(16) float ps[4][32][66];   // [half*2+which][row][col], pad 66 -> 2-way max

    const int tid = threadIdx.x;
    const int w = tid >> 6, l = tid & 63;
    const int lr = l & 15, lk = l >> 4;
    const int rg = w >> 1, kh = w & 1;              // row-group, k-half
    const bool is_q = blockIdx.x < 512;
    const int blk = is_q ? blockIdx.x : blockIdx.x - 512;
    const long rowbase = (long)blk * 32 + rg * 16;
    const int kbase = kh * 256;

    if (is_q) {
        f32x4 acc[4] = {};
        for (int kk = 0; kk < 256; kk += 32) {
            bf16x8 a = load_cvt8(x + (rowbase + lr) * DIM + kbase + kk + lk * 8);
#pragma unroll
            for (int nb = 0; nb < 4; nb++) {
                bf16x8 bw = load_cvt8(Wq + (long)(nb * 16 + lr) * DIM + kbase + kk + lk * 8);
                acc[nb] = __builtin_amdgcn_mfma_f32_16x16x32_bf16(a, bw, acc[nb], 0, 0, 0);
            }
        }
#pragma unroll
        for (int nb = 0; nb < 4; nb++)
#pragma unroll
            for (int i = 0; i < 4; i++)
                ps[kh * 2][rg * 16 + lk * 4 + i][nb * 16 + lr] = acc[nb][i];
        __syncthreads();
        for (int e = tid; e < 2048; e += 256) {
            int row = e >> 6, col = e & 63;
            float v = ps[0][row][col] + ps[2][row][col] + bq[col];
            Qb[((long)blk * 32 + row) * KD + col] = (__bf16)v;
        }
    } else {
        f32x4 acck[4] = {}, accv[4] = {};
        for (int kk = 0; kk < 256; kk += 32) {
            bf16x8 a = load_cvt8(buf + (rowbase + lr) * DIM + kbase + kk + lk * 8);
#pragma unroll
            for (int nb = 0; nb < 4; nb++) {
                bf16x8 bwk = load_cvt8(Wk + (long)(nb * 16 + lr) * DIM + kbase + kk + lk * 8);
                bf16x8 bwv = load_cvt8(Wv + (long)(nb * 16 + lr) * DIM + kbase + kk + lk * 8);
                acck[nb] = __builtin_amdgcn_mfma_f32_16x16x32_bf16(a, bwk, acck[nb], 0, 0, 0);
                accv[nb] = __builtin_amdgcn_mfma_f32_16x16x32_bf16(a, bwv, accv[nb], 0, 0, 0);
            }
        }
#pragma unroll
        for (int nb = 0; nb < 4; nb++)
#pragma unroll
            for (int i = 0; i < 4; i++) {
                ps[kh * 2 + 0][rg * 16 + lk * 4 + i][nb * 16 + lr] = acck[nb][i];
                ps[kh * 2 + 1][rg * 16 + lk * 4 + i][nb * 16 + lr] = accv[nb][i];
            }
        __syncthreads();
        for (int e = tid; e < 2048; e += 256) {       // K: row-major, col-coalesced
            int row = e >> 6, col = e & 63;
            float v = ps[0][row][col] + ps[2][row][col] + bk[col];
            Kb[((long)blk * 32 + row) * KD + col] = (__bf16)v;
        }
        for (int e = tid; e < 2048; e += 256) {       // V: transposed store, kidx-coalesced
            int row = e & 31, col = e >> 5;
            float v = ps[1][row][col] + ps[3][row][col] + bv[col];
            long grow = (long)blk * 32 + row;
            int b = (int)(grow >> 12), kidx = (int)(grow & 4095);
            Vt[((long)b * KD + col) * NK + kidx] = (__bf16)v;
        }
    }
}

// ---- flash attention, split-K. Block = 16 q rows, 8 waves; wave w owns keys [w*512, w*512+512).
__global__ __launch_bounds__(512, 8) void attn_kernel(
        const __bf16* __restrict__ Qb, const __bf16* __restrict__ Kb,
        const __bf16* __restrict__ Vt, const int* __restrict__ mask,
        float* __restrict__ out) {
    // main loop: per-wave P tiles [16][72] bf16 at smem + w*2304 (18432 B used)
    // merge:     o_s[8][16][66] f32 (33792 B) + ml[8][2][16] f32 (1024 B)
    __shared__ __align__(16) char smem[8 * 16 * 66 * 4 + 8 * 2 * 16 * 4];

    const int tid = threadIdx.x;
    const int w = tid >> 6, l = tid & 63;
    const int lr = l & 15, lk = l >> 4;
    const int b = blockIdx.x >> 8;
    const int q0 = (blockIdx.x & 255) * 16;
    const int k0 = w * 512;

    const __bf16* Qp = Qb + ((long)b * NQ + q0) * KD;
    const __bf16* Kp = Kb + (long)b * NK * KD;
    const __bf16* Vp = Vt + (long)b * KD * NK;
    const int*    mp = mask + ((long)b * NQ + q0) * NK;

    __bf16 (*pl)[72] = (__bf16(*)[72])(smem + w * 2304);

    bf16x8 qa[2];
#pragma unroll
    for (int ks = 0; ks < 2; ks++)
        qa[ks] = *(const bf16x8*)(Qp + (long)lr * KD + ks * 32 + lk * 8);

    f32x4 o[4] = {};
    float m_i[4], l_i[4];
#pragma unroll
    for (int i = 0; i < 4; i++) { m_i[i] = -INFINITY; l_i[i] = 0.f; }

    for (int kt = k0; kt < k0 + 512; kt += 64) {
        // ---- S = Q K^T  (16 q x 64 k)
        f32x4 s[4] = {};
#pragma unroll
        for (int ks = 0; ks < 2; ks++)
#pragma unroll
            for (int nb = 0; nb < 4; nb++) {
                bf16x8 kb = *(const bf16x8*)(Kp + (long)(kt + nb * 16 + lr) * KD + ks * 32 + lk * 8);
                s[nb] = __builtin_amdgcn_mfma_f32_16x16x32_bf16(qa[ks], kb, s[nb], 0, 0, 0);
            }
        // ---- scale + mask (C layout: row = lk*4+i, col = nb*16+lr)
#pragma unroll
        for (int nb = 0; nb < 4; nb++)
#pragma unroll
            for (int i = 0; i < 4; i++) {
                int mv = mp[(long)(lk * 4 + i) * NK + kt + nb * 16 + lr];
                s[nb][i] = mv ? s[nb][i] * 0.125f : -1024.0f;
            }
        // ---- online softmax, per row i (reduce across the 16 lr lanes)
#pragma unroll
        for (int i = 0; i < 4; i++) {
            float v = fmaxf(fmaxf(s[0][i], s[1][i]), fmaxf(s[2][i], s[3][i]));
            v = fmaxf(v, __shfl_xor(v, 1));
            v = fmaxf(v, __shfl_xor(v, 2));
            v = fmaxf(v, __shfl_xor(v, 4));
            v = fmaxf(v, __shfl_xor(v, 8));
            float mnew = fmaxf(m_i[i], v);
            float sc = __expf(m_i[i] - mnew);
            m_i[i] = mnew;
            float rs = 0.f;
#pragma unroll
            for (int nb = 0; nb < 4; nb++) {
                float p = __expf(s[nb][i] - mnew);
                s[nb][i] = p;
                rs += p;
            }
            rs += __shfl_xor(rs, 1);
            rs += __shfl_xor(rs, 2);
            rs += __shfl_xor(rs, 4);
            rs += __shfl_xor(rs, 8);
            l_i[i] = l_i[i] * sc + rs;
#pragma unroll
            for (int nb = 0; nb < 4; nb++) o[nb][i] *= sc;
        }
        // ---- P -> LDS (bf16), intra-wave transpose
#pragma unroll
        for (int nb = 0; nb < 4; nb++)
#pragma unroll
            for (int i = 0; i < 4; i++)
                pl[lk * 4 + i][nb * 16 + lr] = (__bf16)s[nb][i];
        // ---- O += P V
#pragma unroll
        for (int ks = 0; ks < 2; ks++) {
            bf16x8 pa = *(const bf16x8*)&pl[lr][ks * 32 + lk * 8];
#pragma unroll
            for (int nb = 0; nb < 4; nb++) {
                bf16x8 vb = *(const bf16x8*)(Vp + (long)(nb * 16 + lr) * NK + kt + ks * 32 + lk * 8);
                o[nb] = __builtin_amdgcn_mfma_f32_16x16x32_bf16(pa, vb, o[nb], 0, 0, 0);
            }
        }
    }

    // ---- split-K merge through LDS
    __syncthreads();                       // everyone done with pl regions
    float* o_s = (float*)smem;             // [8][16][66]
    float* ml  = (float*)(smem + 8 * 16 * 66 * 4);  // [8][2][16]
#pragma unroll
    for (int nb = 0; nb < 4; nb++)
#pragma unroll
        for (int i = 0; i < 4; i++)
            o_s[(w * 16 + lk * 4 + i) * 66 + nb * 16 + lr] = o[nb][i];
    if (lr == 0) {
#pragma unroll
        for (int i = 0; i < 4; i++) {
            ml[w * 32 + lk * 4 + i]      = m_i[i];
            ml[w * 32 + 16 + lk * 4 + i] = l_i[i];
        }
    }
    __syncthreads();
    for (int e = tid; e < 1024; e += 512) {
        int row = e >> 6, col = e & 63;
        float M = -INFINITY;
#pragma unroll
        for (int ww = 0; ww < 8; ww++) M = fmaxf(M, ml[ww * 32 + row]);
        float L = 0.f, O = 0.f;
#pragma unroll
        for (int ww = 0; ww < 8; ww++) {
            float f = __expf(ml[ww * 32 + row] - M);
            L += f * ml[ww * 32 + 16 + row];
            O += f * o_s[(ww * 16 + row) * 66 + col];
        }
        out[((long)b * NQ + q0 + row) * KD + col] = O / L;
    }
}

extern "C" void kernel_launch(void* const* d_in, const int* in_sizes, int n_in,
                              void* d_out, int out_size, void* d_ws, size_t ws_size,
                              hipStream_t stream) {
    const float* x      = (const float*)d_in[0];
    const float* buffer = (const float*)d_in[1];
    const int*   mask   = (const int*)d_in[2];
    const float* Wq     = (const float*)d_in[3];
    const float* bq     = (const float*)d_in[4];
    const float* Wk     = (const float*)d_in[5];
    const float* bk     = (const float*)d_in[6];
    const float* Wv     = (const float*)d_in[7];
    const float* bv     = (const float*)d_in[8];
    float* out = (float*)d_out;

    __bf16* Qb = (__bf16*)d_ws;
    __bf16* Kb = Qb + (size_t)NB * NQ * KD;
    __bf16* Vt = Kb + (size_t)NB * NK * KD;

    proj_kernel<<<dim3(1024), dim3(256), 0, stream>>>(x, buffer, Wq, bq, Wk, bk, Wv, bv, Qb, Kb, Vt);
    attn_kernel<<<dim3(NB * (NQ / 16)), dim3(512), 0, stream>>>(Qb, Kb, Vt, mask, out);
}

// Round 3
// 282.402 us; speedup vs baseline: 1.3355x; 1.3355x over previous
//
#include <hip/hip_runtime.h>
#include <hip/hip_bf16.h>

typedef float f32x4 __attribute__((ext_vector_type(4)));
typedef __bf16 bf16x8 __attribute__((ext_vector_type(8)));

#define NB 4        // batch
#define NQ 4096
#define NK 4096
#define DIM 512
#define KD 64

__device__ inline bf16x8 load_cvt8(const float* __restrict__ p) {
    float4 f0 = *(const float4*)p;
    float4 f1 = *(const float4*)(p + 4);
    bf16x8 r;
    r[0] = (__bf16)f0.x; r[1] = (__bf16)f0.y; r[2] = (__bf16)f0.z; r[3] = (__bf16)f0.w;
    r[4] = (__bf16)f1.x; r[5] = (__bf16)f1.y; r[6] = (__bf16)f1.z; r[7] = (__bf16)f1.w;
    return r;
}

// ---- fused Q + K/V projection, 16 rows/wave, K-split 2, LDS f32 reduce.
// blocks 0..511: Q rows (32/block). blocks 512..1023: K/V rows (32/block).
__global__ __launch_bounds__(256, 4) void proj_kernel(
        const float* __restrict__ x, const float* __restrict__ buf,
        const float* __restrict__ Wq, const float* __restrict__ bq,
        const float* __restrict__ Wk, const float* __restrict__ bk,
        const float* __restrict__ Wv, const float* __restrict__ bv,
        __bf16* __restrict__ Qb, __bf16* __restrict__ Kb, __bf16* __restrict__ Vt) {
    __shared__ __align__(16) float ps[4][32][66];   // [half*2+which][row][col]

    const int tid = threadIdx.x;
    const int w = tid >> 6, l = tid & 63;
    const int lr = l & 15, lk = l >> 4;
    const int rg = w >> 1, kh = w & 1;              // row-group, k-half
    const bool is_q = blockIdx.x < 512;
    const int blk = is_q ? blockIdx.x : blockIdx.x - 512;
    const long rowbase = (long)blk * 32 + rg * 16;
    const int kbase = kh * 256;

    if (is_q) {
        f32x4 acc[4] = {};
        for (int kk = 0; kk < 256; kk += 32) {
            bf16x8 a = load_cvt8(x + (rowbase + lr) * DIM + kbase + kk + lk * 8);
#pragma unroll
            for (int nb = 0; nb < 4; nb++) {
                bf16x8 bw = load_cvt8(Wq + (long)(nb * 16 + lr) * DIM + kbase + kk + lk * 8);
                acc[nb] = __builtin_amdgcn_mfma_f32_16x16x32_bf16(a, bw, acc[nb], 0, 0, 0);
            }
        }
#pragma unroll
        for (int nb = 0; nb < 4; nb++)
#pragma unroll
            for (int i = 0; i < 4; i++)
                ps[kh * 2][rg * 16 + lk * 4 + i][nb * 16 + lr] = acc[nb][i];
        __syncthreads();
        for (int e = tid; e < 2048; e += 256) {
            int row = e >> 6, col = e & 63;
            float v = ps[0][row][col] + ps[2][row][col] + bq[col];
            Qb[((long)blk * 32 + row) * KD + col] = (__bf16)v;
        }
    } else {
        f32x4 acck[4] = {}, accv[4] = {};
        for (int kk = 0; kk < 256; kk += 32) {
            bf16x8 a = load_cvt8(buf + (rowbase + lr) * DIM + kbase + kk + lk * 8);
#pragma unroll
            for (int nb = 0; nb < 4; nb++) {
                bf16x8 bwk = load_cvt8(Wk + (long)(nb * 16 + lr) * DIM + kbase + kk + lk * 8);
                bf16x8 bwv = load_cvt8(Wv + (long)(nb * 16 + lr) * DIM + kbase + kk + lk * 8);
                acck[nb] = __builtin_amdgcn_mfma_f32_16x16x32_bf16(a, bwk, acck[nb], 0, 0, 0);
                accv[nb] = __builtin_amdgcn_mfma_f32_16x16x32_bf16(a, bwv, accv[nb], 0, 0, 0);
            }
        }
#pragma unroll
        for (int nb = 0; nb < 4; nb++)
#pragma unroll
            for (int i = 0; i < 4; i++) {
                ps[kh * 2 + 0][rg * 16 + lk * 4 + i][nb * 16 + lr] = acck[nb][i];
                ps[kh * 2 + 1][rg * 16 + lk * 4 + i][nb * 16 + lr] = accv[nb][i];
            }
        __syncthreads();
        for (int e = tid; e < 2048; e += 256) {       // K: row-major, col-coalesced
            int row = e >> 6, col = e & 63;
            float v = ps[0][row][col] + ps[2][row][col] + bk[col];
            Kb[((long)blk * 32 + row) * KD + col] = (__bf16)v;
        }
        for (int e = tid; e < 2048; e += 256) {       // V: transposed store, kidx-coalesced
            int row = e & 31, col = e >> 5;
            float v = ps[1][row][col] + ps[3][row][col] + bv[col];
            long grow = (long)blk * 32 + row;
            int b = (int)(grow >> 12), kidx = (int)(grow & 4095);
            Vt[((long)b * KD + col) * NK + kidx] = (__bf16)v;
        }
    }
}

// ---- flash attention, split-K by 4. Block = 16 q rows, 4 waves; wave w owns keys [w*1024, w*1024+1024).
__global__ __launch_bounds__(256, 4) void attn_kernel(
        const __bf16* __restrict__ Qb, const __bf16* __restrict__ Kb,
        const __bf16* __restrict__ Vt, const int* __restrict__ mask,
        float* __restrict__ out) {
    // main loop: per-wave P tiles [16][72] bf16 at smem + w*2304 (9216 B used)
    // merge:     o_s[4][16][66] f32 (16896 B) + ml[4][2][16] f32 (512 B)
    __shared__ __align__(16) char smem[4 * 16 * 66 * 4 + 4 * 2 * 16 * 4];

    const int tid = threadIdx.x;
    const int w = tid >> 6, l = tid & 63;
    const int lr = l & 15, lk = l >> 4;
    const int b = blockIdx.x >> 8;
    const int q0 = (blockIdx.x & 255) * 16;
    const int k0 = w * 1024;

    const __bf16* Qp = Qb + ((long)b * NQ + q0) * KD;
    const __bf16* Kp = Kb + (long)b * NK * KD;
    const __bf16* Vp = Vt + (long)b * KD * NK;
    const int*    mp = mask + ((long)b * NQ + q0) * NK;

    __bf16 (*pl)[72] = (__bf16(*)[72])(smem + w * 2304);

    bf16x8 qa[2];
#pragma unroll
    for (int ks = 0; ks < 2; ks++)
        qa[ks] = *(const bf16x8*)(Qp + (long)lr * KD + ks * 32 + lk * 8);

    f32x4 o[4] = {};
    float m_i[4], l_i[4];
#pragma unroll
    for (int i = 0; i < 4; i++) { m_i[i] = -INFINITY; l_i[i] = 0.f; }

    for (int kt = k0; kt < k0 + 1024; kt += 64) {
        // ---- S = Q K^T  (16 q x 64 k)
        f32x4 s[4] = {};
#pragma unroll
        for (int ks = 0; ks < 2; ks++)
#pragma unroll
            for (int nb = 0; nb < 4; nb++) {
                bf16x8 kb = *(const bf16x8*)(Kp + (long)(kt + nb * 16 + lr) * KD + ks * 32 + lk * 8);
                s[nb] = __builtin_amdgcn_mfma_f32_16x16x32_bf16(qa[ks], kb, s[nb], 0, 0, 0);
            }
        // ---- scale + mask (C layout: row = lk*4+i, col = nb*16+lr)
#pragma unroll
        for (int nb = 0; nb < 4; nb++)
#pragma unroll
            for (int i = 0; i < 4; i++) {
                int mv = mp[(long)(lk * 4 + i) * NK + kt + nb * 16 + lr];
                s[nb][i] = mv ? s[nb][i] * 0.125f : -1024.0f;
            }
        // ---- online softmax, per row i (reduce across the 16 lr lanes)
#pragma unroll
        for (int i = 0; i < 4; i++) {
            float v = fmaxf(fmaxf(s[0][i], s[1][i]), fmaxf(s[2][i], s[3][i]));
            v = fmaxf(v, __shfl_xor(v, 1));
            v = fmaxf(v, __shfl_xor(v, 2));
            v = fmaxf(v, __shfl_xor(v, 4));
            v = fmaxf(v, __shfl_xor(v, 8));
            float mnew = fmaxf(m_i[i], v);
            float sc = __expf(m_i[i] - mnew);
            m_i[i] = mnew;
            float rs = 0.f;
#pragma unroll
            for (int nb = 0; nb < 4; nb++) {
                float p = __expf(s[nb][i] - mnew);
                s[nb][i] = p;
                rs += p;
            }
            rs += __shfl_xor(rs, 1);
            rs += __shfl_xor(rs, 2);
            rs += __shfl_xor(rs, 4);
            rs += __shfl_xor(rs, 8);
            l_i[i] = l_i[i] * sc + rs;
#pragma unroll
            for (int nb = 0; nb < 4; nb++) o[nb][i] *= sc;
        }
        // ---- P -> LDS (bf16), intra-wave transpose
#pragma unroll
        for (int nb = 0; nb < 4; nb++)
#pragma unroll
            for (int i = 0; i < 4; i++)
                pl[lk * 4 + i][nb * 16 + lr] = (__bf16)s[nb][i];
        // ---- O += P V
#pragma unroll
        for (int ks = 0; ks < 2; ks++) {
            bf16x8 pa = *(const bf16x8*)&pl[lr][ks * 32 + lk * 8];
#pragma unroll
            for (int nb = 0; nb < 4; nb++) {
                bf16x8 vb = *(const bf16x8*)(Vp + (long)(nb * 16 + lr) * NK + kt + ks * 32 + lk * 8);
                o[nb] = __builtin_amdgcn_mfma_f32_16x16x32_bf16(pa, vb, o[nb], 0, 0, 0);
            }
        }
    }

    // ---- split-K merge through LDS
    __syncthreads();                       // everyone done with pl regions
    float* o_s = (float*)smem;             // [4][16][66]
    float* ml  = (float*)(smem + 4 * 16 * 66 * 4);  // [4][2][16]
#pragma unroll
    for (int nb = 0; nb < 4; nb++)
#pragma unroll
        for (int i = 0; i < 4; i++)
            o_s[(w * 16 + lk * 4 + i) * 66 + nb * 16 + lr] = o[nb][i];
    if (lr == 0) {
#pragma unroll
        for (int i = 0; i < 4; i++) {
            ml[w * 32 + lk * 4 + i]      = m_i[i];
            ml[w * 32 + 16 + lk * 4 + i] = l_i[i];
        }
    }
    __syncthreads();
    for (int e = tid; e < 1024; e += 256) {
        int row = e >> 6, col = e & 63;
        float M = -INFINITY;
#pragma unroll
        for (int ww = 0; ww < 4; ww++) M = fmaxf(M, ml[ww * 32 + row]);
        float L = 0.f, O = 0.f;
#pragma unroll
        for (int ww = 0; ww < 4; ww++) {
            float f = __expf(ml[ww * 32 + row] - M);
            L += f * ml[ww * 32 + 16 + row];
            O += f * o_s[(ww * 16 + row) * 66 + col];
        }
        out[((long)b * NQ + q0 + row) * KD + col] = O / L;
    }
}

extern "C" void kernel_launch(void* const* d_in, const int* in_sizes, int n_in,
                              void* d_out, int out_size, void* d_ws, size_t ws_size,
                              hipStream_t stream) {
    const float* x      = (const float*)d_in[0];
    const float* buffer = (const float*)d_in[1];
    const int*   mask   = (const int*)d_in[2];
    const float* Wq     = (const float*)d_in[3];
    const float* bq     = (const float*)d_in[4];
    const float* Wk     = (const float*)d_in[5];
    const float* bk     = (const float*)d_in[6];
    const float* Wv     = (const float*)d_in[7];
    const float* bv     = (const float*)d_in[8];
    float* out = (float*)d_out;

    __bf16* Qb = (__bf16*)d_ws;
    __bf16* Kb = Qb + (size_t)NB * NQ * KD;
    __bf16* Vt = Kb + (size_t)NB * NK * KD;

    proj_kernel<<<dim3(1024), dim3(256), 0, stream>>>(x, buffer, Wq, bq, Wk, bk, Wv, bv, Qb, Kb, Vt);
    attn_kernel<<<dim3(NB * (NQ / 16)), dim3(256), 0, stream>>>(Qb, Kb, Vt, mask, out);
}

// Round 4
// 236.100 us; speedup vs baseline: 1.5974x; 1.1961x over previous
//
#include <hip/hip_runtime.h>
#include <hip/hip_bf16.h>

typedef float f32x4 __attribute__((ext_vector_type(4)));
typedef __bf16 bf16x8 __attribute__((ext_vector_type(8)));

#define NB 4        // batch
#define NQ 4096
#define NK 4096
#define DIM 512
#define KD 64
#define PKW 128     // packed mask words per row = NK/32

#define PACK_BLOCKS 8192   // 8192 blocks * 256 thr * 32 ints = 67.1M mask ints

__device__ inline bf16x8 load_cvt8(const float* __restrict__ p) {
    float4 f0 = *(const float4*)p;
    float4 f1 = *(const float4*)(p + 4);
    bf16x8 r;
    r[0] = (__bf16)f0.x; r[1] = (__bf16)f0.y; r[2] = (__bf16)f0.z; r[3] = (__bf16)f0.w;
    r[4] = (__bf16)f1.x; r[5] = (__bf16)f1.y; r[6] = (__bf16)f1.z; r[7] = (__bf16)f1.w;
    return r;
}

// ---- fused prep: mask bit-pack (blocks < PACK_BLOCKS) + Q/K/V projections.
// Pack blocks stream 268 MB of mask; proj blocks' MFMA work hides under that stream.
__global__ __launch_bounds__(256, 4) void prep_kernel(
        const float* __restrict__ x, const float* __restrict__ buf,
        const int* __restrict__ mask,
        const float* __restrict__ Wq, const float* __restrict__ bq,
        const float* __restrict__ Wk, const float* __restrict__ bk,
        const float* __restrict__ Wv, const float* __restrict__ bv,
        __bf16* __restrict__ Qb, __bf16* __restrict__ Kb, __bf16* __restrict__ Vt,
        unsigned* __restrict__ pk) {
    __shared__ __align__(16) float ps[4][32][66];

    const int tid = threadIdx.x;

    if (blockIdx.x < PACK_BLOCKS) {
        // ---- mask bit-pack: thread t packs ints [32t, 32t+32) -> pk[t]
        long t = (long)blockIdx.x * 256 + tid;
        const int4* p4 = (const int4*)(mask + t * 32);
        unsigned r = 0;
#pragma unroll
        for (int j = 0; j < 8; j++) {
            int4 v = p4[j];
            r |= (v.x ? 1u : 0u) << (j * 4 + 0);
            r |= (v.y ? 1u : 0u) << (j * 4 + 1);
            r |= (v.z ? 1u : 0u) << (j * 4 + 2);
            r |= (v.w ? 1u : 0u) << (j * 4 + 3);
        }
        pk[t] = r;
        return;
    }

    const int w = tid >> 6, l = tid & 63;
    const int lr = l & 15, lk = l >> 4;
    const int rg = w >> 1, kh = w & 1;              // row-group, k-half
    const bool is_q = blockIdx.x < PACK_BLOCKS + 512;
    const int blk = is_q ? blockIdx.x - PACK_BLOCKS : blockIdx.x - PACK_BLOCKS - 512;
    const long rowbase = (long)blk * 32 + rg * 16;
    const int kbase = kh * 256;

    if (is_q) {
        f32x4 acc[4] = {};
        for (int kk = 0; kk < 256; kk += 32) {
            bf16x8 a = load_cvt8(x + (rowbase + lr) * DIM + kbase + kk + lk * 8);
#pragma unroll
            for (int nb = 0; nb < 4; nb++) {
                bf16x8 bw = load_cvt8(Wq + (long)(nb * 16 + lr) * DIM + kbase + kk + lk * 8);
                acc[nb] = __builtin_amdgcn_mfma_f32_16x16x32_bf16(a, bw, acc[nb], 0, 0, 0);
            }
        }
#pragma unroll
        for (int nb = 0; nb < 4; nb++)
#pragma unroll
            for (int i = 0; i < 4; i++)
                ps[kh * 2][rg * 16 + lk * 4 + i][nb * 16 + lr] = acc[nb][i];
        __syncthreads();
        for (int e = tid; e < 2048; e += 256) {
            int row = e >> 6, col = e & 63;
            float v = ps[0][row][col] + ps[2][row][col] + bq[col];
            Qb[((long)blk * 32 + row) * KD + col] = (__bf16)v;
        }
    } else {
        f32x4 acck[4] = {}, accv[4] = {};
        for (int kk = 0; kk < 256; kk += 32) {
            bf16x8 a = load_cvt8(buf + (rowbase + lr) * DIM + kbase + kk + lk * 8);
#pragma unroll
            for (int nb = 0; nb < 4; nb++) {
                bf16x8 bwk = load_cvt8(Wk + (long)(nb * 16 + lr) * DIM + kbase + kk + lk * 8);
                bf16x8 bwv = load_cvt8(Wv + (long)(nb * 16 + lr) * DIM + kbase + kk + lk * 8);
                acck[nb] = __builtin_amdgcn_mfma_f32_16x16x32_bf16(a, bwk, acck[nb], 0, 0, 0);
                accv[nb] = __builtin_amdgcn_mfma_f32_16x16x32_bf16(a, bwv, accv[nb], 0, 0, 0);
            }
        }
#pragma unroll
        for (int nb = 0; nb < 4; nb++)
#pragma unroll
            for (int i = 0; i < 4; i++) {
                ps[kh * 2 + 0][rg * 16 + lk * 4 + i][nb * 16 + lr] = acck[nb][i];
                ps[kh * 2 + 1][rg * 16 + lk * 4 + i][nb * 16 + lr] = accv[nb][i];
            }
        __syncthreads();
        for (int e = tid; e < 2048; e += 256) {       // K: row-major, col-coalesced
            int row = e >> 6, col = e & 63;
            float v = ps[0][row][col] + ps[2][row][col] + bk[col];
            Kb[((long)blk * 32 + row) * KD + col] = (__bf16)v;
        }
        for (int e = tid; e < 2048; e += 256) {       // V: transposed store, kidx-coalesced
            int row = e & 31, col = e >> 5;
            float v = ps[1][row][col] + ps[3][row][col] + bv[col];
            long grow = (long)blk * 32 + row;
            int b = (int)(grow >> 12), kidx = (int)(grow & 4095);
            Vt[((long)b * KD + col) * NK + kidx] = (__bf16)v;
        }
    }
}

// ---- flash attention, split-K by 4, fixed-max softmax (logits bounded; masked -> p = 0).
// Block = 16 q rows, 4 waves; wave w owns keys [w*1024, w*1024+1024).
__global__ __launch_bounds__(256, 4) void attn_kernel(
        const __bf16* __restrict__ Qb, const __bf16* __restrict__ Kb,
        const __bf16* __restrict__ Vt, const unsigned* __restrict__ pk,
        float* __restrict__ out) {
    // phase 1: per-wave double P tiles: [2][16][72] bf16 at w*4608 (18432 B total)
    // phase 2 (after barrier, reuse): o_s[4][16][66] f32 (16896 B) + ml[4][16] f32 (256 B)
    __shared__ __align__(16) char smem[18432];

    const int tid = threadIdx.x;
    const int w = tid >> 6, l = tid & 63;
    const int lr = l & 15, lk = l >> 4;
    const int b = blockIdx.x >> 8;
    const int q0 = (blockIdx.x & 255) * 16;
    const int k0 = w * 1024;

    const __bf16* Qp = Qb + ((long)b * NQ + q0) * KD;
    const __bf16* Kp = Kb + (long)b * NK * KD;
    const __bf16* Vp = Vt + (long)b * KD * NK;
    const unsigned* mp = pk + ((long)b * NQ + q0) * PKW;

    __bf16 (*pl0)[72] = (__bf16(*)[72])(smem + w * 4608);
    __bf16 (*pl1)[72] = (__bf16(*)[72])(smem + w * 4608 + 2304);

    bf16x8 qa[2];
#pragma unroll
    for (int ks = 0; ks < 2; ks++)
        qa[ks] = *(const bf16x8*)(Qp + (long)lr * KD + ks * 32 + lk * 8);

    f32x4 o[4] = {};
    float l_i[4] = {0.f, 0.f, 0.f, 0.f};

    auto tile = [&](int kt, __bf16 (*pl)[72]) {
        // ---- S = Q K^T  (16 q x 64 k)
        f32x4 s[4] = {};
#pragma unroll
        for (int ks = 0; ks < 2; ks++)
#pragma unroll
            for (int nb = 0; nb < 4; nb++) {
                bf16x8 kb = *(const bf16x8*)(Kp + (long)(kt + nb * 16 + lr) * KD + ks * 32 + lk * 8);
                s[nb] = __builtin_amdgcn_mfma_f32_16x16x32_bf16(qa[ks], kb, s[nb], 0, 0, 0);
            }
        // ---- packed mask words: per row i, 2 dwords cover keys [kt, kt+64)
        unsigned mw0[4], mw1[4];
#pragma unroll
        for (int i = 0; i < 4; i++) {
            uint2 mwv = *(const uint2*)(mp + (long)(lk * 4 + i) * PKW + (kt >> 5));
            mw0[i] = mwv.x; mw1[i] = mwv.y;
        }
        // ---- fixed-max softmax numerator: p = mask ? exp(s/8) : 0   (C layout: row=lk*4+i, col=nb*16+lr)
#pragma unroll
        for (int nb = 0; nb < 4; nb++) {
            const unsigned bit = (unsigned)((nb * 16 + lr) & 31);
#pragma unroll
            for (int i = 0; i < 4; i++) {
                unsigned wv = (nb < 2) ? mw0[i] : mw1[i];
                float e = __expf(s[nb][i] * 0.125f);
                float p = ((wv >> bit) & 1u) ? e : 0.0f;
                __bf16 pb = (__bf16)p;
                pl[lk * 4 + i][nb * 16 + lr] = pb;
                l_i[i] += (float)pb;       // denom from the same bf16-rounded values
            }
        }
        // ---- O += P V
#pragma unroll
        for (int ks = 0; ks < 2; ks++) {
            bf16x8 pa = *(const bf16x8*)&pl[lr][ks * 32 + lk * 8];
#pragma unroll
            for (int nb = 0; nb < 4; nb++) {
                bf16x8 vb = *(const bf16x8*)(Vp + (long)(nb * 16 + lr) * NK + kt + ks * 32 + lk * 8);
                o[nb] = __builtin_amdgcn_mfma_f32_16x16x32_bf16(pa, vb, o[nb], 0, 0, 0);
            }
        }
    };

#pragma unroll 1
    for (int kt = k0; kt < k0 + 1024; kt += 128) {
        tile(kt, pl0);
        tile(kt + 64, pl1);
    }

    // ---- reduce denom across the 16 lr lanes (once, at the end)
#pragma unroll
    for (int i = 0; i < 4; i++) {
        float v = l_i[i];
        v += __shfl_xor(v, 1);
        v += __shfl_xor(v, 2);
        v += __shfl_xor(v, 4);
        v += __shfl_xor(v, 8);
        l_i[i] = v;
    }

    // ---- split-K merge: plain sums of (o, l)
    __syncthreads();                                  // all waves done with pl regions
    float* o_s = (float*)smem;                        // [4][16][66]
    float* ml  = (float*)(smem + 4 * 16 * 66 * 4);    // [4][16]
#pragma unroll
    for (int nb = 0; nb < 4; nb++)
#pragma unroll
        for (int i = 0; i < 4; i++)
            o_s[(w * 16 + lk * 4 + i) * 66 + nb * 16 + lr] = o[nb][i];
    if (lr == 0) {
#pragma unroll
        for (int i = 0; i < 4; i++)
            ml[w * 16 + lk * 4 + i] = l_i[i];
    }
    __syncthreads();
    for (int e = tid; e < 1024; e += 256) {
        int row = e >> 6, col = e & 63;
        float L = ml[row] + ml[16 + row] + ml[32 + row] + ml[48 + row];
        float O = 0.f;
#pragma unroll
        for (int ww = 0; ww < 4; ww++)
            O += o_s[(ww * 16 + row) * 66 + col];
        out[((long)b * NQ + q0 + row) * KD + col] = O / L;
    }
}

extern "C" void kernel_launch(void* const* d_in, const int* in_sizes, int n_in,
                              void* d_out, int out_size, void* d_ws, size_t ws_size,
                              hipStream_t stream) {
    const float* x      = (const float*)d_in[0];
    const float* buffer = (const float*)d_in[1];
    const int*   mask   = (const int*)d_in[2];
    const float* Wq     = (const float*)d_in[3];
    const float* bq     = (const float*)d_in[4];
    const float* Wk     = (const float*)d_in[5];
    const float* bk     = (const float*)d_in[6];
    const float* Wv     = (const float*)d_in[7];
    const float* bv     = (const float*)d_in[8];
    float* out = (float*)d_out;

    unsigned* pk = (unsigned*)d_ws;                               // 8.39 MB
    __bf16* Qb = (__bf16*)((char*)d_ws + (size_t)NB * NQ * PKW * 4);
    __bf16* Kb = Qb + (size_t)NB * NQ * KD;
    __bf16* Vt = Kb + (size_t)NB * NK * KD;

    prep_kernel<<<dim3(PACK_BLOCKS + 1024), dim3(256), 0, stream>>>(
        x, buffer, mask, Wq, bq, Wk, bk, Wv, bv, Qb, Kb, Vt, pk);
    attn_kernel<<<dim3(NB * (NQ / 16)), dim3(256), 0, stream>>>(Qb, Kb, Vt, pk, out);
}

// Round 5
// 226.131 us; speedup vs baseline: 1.6678x; 1.0441x over previous
//
#include <hip/hip_runtime.h>
#include <hip/hip_bf16.h>

typedef float f32x4 __attribute__((ext_vector_type(4)));
typedef __bf16 bf16x8 __attribute__((ext_vector_type(8)));
typedef unsigned long long u64;
typedef u64 u64x2 __attribute__((ext_vector_type(2)));

#define NB 4        // batch
#define NQ 4096
#define NK 4096
#define DIM 512
#define KD 64
#define PKW 128     // packed mask words (u32) per row = NK/32
#define NG64 (1 << 20)      // 64-bit mask groups total = NB*NQ*NK/64
#define PACK_BLOCKS 2048
#define PACK_WAVES (PACK_BLOCKS * 4)

__device__ inline bf16x8 load_cvt8(const float* __restrict__ p) {
    float4 f0 = *(const float4*)p;
    float4 f1 = *(const float4*)(p + 4);
    bf16x8 r;
    r[0] = (__bf16)f0.x; r[1] = (__bf16)f0.y; r[2] = (__bf16)f0.z; r[3] = (__bf16)f0.w;
    r[4] = (__bf16)f1.x; r[5] = (__bf16)f1.y; r[6] = (__bf16)f1.z; r[7] = (__bf16)f1.w;
    return r;
}

// ---- fused prep: Q/K/V projections (blocks 0..1023) + ballot mask-pack (blocks 1024..3071).
// Proj blocks first: they fill the machine (1024 = 4/CU exactly), pack streams in behind.
__global__ __launch_bounds__(256, 4) void prep_kernel(
        const float* __restrict__ x, const float* __restrict__ buf,
        const int* __restrict__ mask,
        const float* __restrict__ Wq, const float* __restrict__ bq,
        const float* __restrict__ Wk, const float* __restrict__ bk,
        const float* __restrict__ Wv, const float* __restrict__ bv,
        __bf16* __restrict__ Qb, __bf16* __restrict__ Kb, __bf16* __restrict__ Vt,
        unsigned* __restrict__ pk) {
    __shared__ __align__(16) float ps[4][32][66];

    const int tid = threadIdx.x;
    const int w = tid >> 6, l = tid & 63;

    if (blockIdx.x >= 1024) {
        // ---- mask pack: lane l reads int (g*64 + l); ballot = the 64 bits of group g.
        const int wid = (blockIdx.x - 1024) * 4 + w;       // 0..8191
        u64* pk64 = (u64*)pk;
        for (int g0 = wid * 4; g0 < NG64; g0 += PACK_WAVES * 4) {
            const int* mb = mask + (long)g0 * 64 + l;
            int m0 = mb[0];
            int m1 = mb[64];
            int m2 = mb[128];
            int m3 = mb[192];
            u64 b0 = __ballot(m0 != 0);
            u64 b1 = __ballot(m1 != 0);
            u64 b2 = __ballot(m2 != 0);
            u64 b3 = __ballot(m3 != 0);
            if (l == 0) {
                u64x2 v01 = {b0, b1}, v23 = {b2, b3};
                *(u64x2*)(pk64 + g0)     = v01;
                *(u64x2*)(pk64 + g0 + 2) = v23;
            }
        }
        return;
    }

    const int lr = l & 15, lk = l >> 4;
    const int rg = w >> 1, kh = w & 1;              // row-group, k-half
    const bool is_q = blockIdx.x < 512;
    const int blk = is_q ? blockIdx.x : blockIdx.x - 512;
    const long rowbase = (long)blk * 32 + rg * 16;
    const int kbase = kh * 256;

    if (is_q) {
        f32x4 acc[4] = {};
        for (int kk = 0; kk < 256; kk += 32) {
            bf16x8 a = load_cvt8(x + (rowbase + lr) * DIM + kbase + kk + lk * 8);
#pragma unroll
            for (int nb = 0; nb < 4; nb++) {
                bf16x8 bw = load_cvt8(Wq + (long)(nb * 16 + lr) * DIM + kbase + kk + lk * 8);
                acc[nb] = __builtin_amdgcn_mfma_f32_16x16x32_bf16(a, bw, acc[nb], 0, 0, 0);
            }
        }
#pragma unroll
        for (int nb = 0; nb < 4; nb++)
#pragma unroll
            for (int i = 0; i < 4; i++)
                ps[kh * 2][rg * 16 + lk * 4 + i][nb * 16 + lr] = acc[nb][i];
        __syncthreads();
        for (int e = tid; e < 2048; e += 256) {
            int row = e >> 6, col = e & 63;
            float v = ps[0][row][col] + ps[2][row][col] + bq[col];
            Qb[((long)blk * 32 + row) * KD + col] = (__bf16)v;
        }
    } else {
        f32x4 acck[4] = {}, accv[4] = {};
        for (int kk = 0; kk < 256; kk += 32) {
            bf16x8 a = load_cvt8(buf + (rowbase + lr) * DIM + kbase + kk + lk * 8);
#pragma unroll
            for (int nb = 0; nb < 4; nb++) {
                bf16x8 bwk = load_cvt8(Wk + (long)(nb * 16 + lr) * DIM + kbase + kk + lk * 8);
                bf16x8 bwv = load_cvt8(Wv + (long)(nb * 16 + lr) * DIM + kbase + kk + lk * 8);
                acck[nb] = __builtin_amdgcn_mfma_f32_16x16x32_bf16(a, bwk, acck[nb], 0, 0, 0);
                accv[nb] = __builtin_amdgcn_mfma_f32_16x16x32_bf16(a, bwv, accv[nb], 0, 0, 0);
            }
        }
#pragma unroll
        for (int nb = 0; nb < 4; nb++)
#pragma unroll
            for (int i = 0; i < 4; i++) {
                ps[kh * 2 + 0][rg * 16 + lk * 4 + i][nb * 16 + lr] = acck[nb][i];
                ps[kh * 2 + 1][rg * 16 + lk * 4 + i][nb * 16 + lr] = accv[nb][i];
            }
        __syncthreads();
        for (int e = tid; e < 2048; e += 256) {       // K: row-major, col-coalesced
            int row = e >> 6, col = e & 63;
            float v = ps[0][row][col] + ps[2][row][col] + bk[col];
            Kb[((long)blk * 32 + row) * KD + col] = (__bf16)v;
        }
        for (int e = tid; e < 2048; e += 256) {       // V: transposed store, kidx-coalesced
            int row = e & 31, col = e >> 5;
            float v = ps[1][row][col] + ps[3][row][col] + bv[col];
            long grow = (long)blk * 32 + row;
            int b = (int)(grow >> 12), kidx = (int)(grow & 4095);
            Vt[((long)b * KD + col) * NK + kidx] = (__bf16)v;
        }
    }
}

// ---- flash attention, split-K by 8, fixed-max softmax (logits bounded; masked -> p = 0).
// Block = 16 q rows, 8 waves; wave w owns keys [w*512, w*512+512).
__global__ __launch_bounds__(512, 4) void attn_kernel(
        const __bf16* __restrict__ Qb, const __bf16* __restrict__ Kb,
        const __bf16* __restrict__ Vt, const unsigned* __restrict__ pk,
        float* __restrict__ out) {
    // phase 1: per-wave double P tiles: [2][16][72] bf16 at w*4608 (36864 B total)
    // phase 2 (after barrier, reuse): o_s[8][16][66] f32 (33792 B) + ml[8][16] f32 (512 B)
    __shared__ __align__(16) char smem[36864];

    const int tid = threadIdx.x;
    const int w = tid >> 6, l = tid & 63;
    const int lr = l & 15, lk = l >> 4;
    const int b = blockIdx.x >> 8;
    const int q0 = (blockIdx.x & 255) * 16;
    const int k0 = w * 512;

    const __bf16* Qp = Qb + ((long)b * NQ + q0) * KD;
    const __bf16* Kp = Kb + (long)b * NK * KD;
    const __bf16* Vp = Vt + (long)b * KD * NK;
    const unsigned* mp = pk + ((long)b * NQ + q0) * PKW;

    __bf16 (*pl0)[72] = (__bf16(*)[72])(smem + w * 4608);
    __bf16 (*pl1)[72] = (__bf16(*)[72])(smem + w * 4608 + 2304);

    bf16x8 qa[2];
#pragma unroll
    for (int ks = 0; ks < 2; ks++)
        qa[ks] = *(const bf16x8*)(Qp + (long)lr * KD + ks * 32 + lk * 8);

    f32x4 o[4] = {};
    float l_i[4] = {0.f, 0.f, 0.f, 0.f};

    auto tile = [&](int kt, __bf16 (*pl)[72]) {
        // ---- S = Q K^T  (16 q x 64 k)
        f32x4 s[4] = {};
#pragma unroll
        for (int ks = 0; ks < 2; ks++)
#pragma unroll
            for (int nb = 0; nb < 4; nb++) {
                bf16x8 kb = *(const bf16x8*)(Kp + (long)(kt + nb * 16 + lr) * KD + ks * 32 + lk * 8);
                s[nb] = __builtin_amdgcn_mfma_f32_16x16x32_bf16(qa[ks], kb, s[nb], 0, 0, 0);
            }
        // ---- packed mask words: per row i, 2 dwords cover keys [kt, kt+64)
        unsigned mw0[4], mw1[4];
#pragma unroll
        for (int i = 0; i < 4; i++) {
            uint2 mwv = *(const uint2*)(mp + (long)(lk * 4 + i) * PKW + (kt >> 5));
            mw0[i] = mwv.x; mw1[i] = mwv.y;
        }
        // ---- fixed-max softmax numerator: p = mask ? exp(s/8) : 0   (C layout: row=lk*4+i, col=nb*16+lr)
#pragma unroll
        for (int nb = 0; nb < 4; nb++) {
            const unsigned bit = (unsigned)((nb * 16 + lr) & 31);
#pragma unroll
            for (int i = 0; i < 4; i++) {
                unsigned wv = (nb < 2) ? mw0[i] : mw1[i];
                float e = __expf(s[nb][i] * 0.125f);
                float p = ((wv >> bit) & 1u) ? e : 0.0f;
                __bf16 pb = (__bf16)p;
                pl[lk * 4 + i][nb * 16 + lr] = pb;
                l_i[i] += (float)pb;       // denom from the same bf16-rounded values
            }
        }
        // ---- O += P V
#pragma unroll
        for (int ks = 0; ks < 2; ks++) {
            bf16x8 pa = *(const bf16x8*)&pl[lr][ks * 32 + lk * 8];
#pragma unroll
            for (int nb = 0; nb < 4; nb++) {
                bf16x8 vb = *(const bf16x8*)(Vp + (long)(nb * 16 + lr) * NK + kt + ks * 32 + lk * 8);
                o[nb] = __builtin_amdgcn_mfma_f32_16x16x32_bf16(pa, vb, o[nb], 0, 0, 0);
            }
        }
    };

#pragma unroll 1
    for (int kt = k0; kt < k0 + 512; kt += 128) {
        tile(kt, pl0);
        tile(kt + 64, pl1);
    }

    // ---- reduce denom across the 16 lr lanes (once, at the end)
#pragma unroll
    for (int i = 0; i < 4; i++) {
        float v = l_i[i];
        v += __shfl_xor(v, 1);
        v += __shfl_xor(v, 2);
        v += __shfl_xor(v, 4);
        v += __shfl_xor(v, 8);
        l_i[i] = v;
    }

    // ---- split-K merge: plain sums of (o, l)
    __syncthreads();                                  // all waves done with pl regions
    float* o_s = (float*)smem;                        // [8][16][66]
    float* ml  = (float*)(smem + 8 * 16 * 66 * 4);    // [8][16]
#pragma unroll
    for (int nb = 0; nb < 4; nb++)
#pragma unroll
        for (int i = 0; i < 4; i++)
            o_s[(w * 16 + lk * 4 + i) * 66 + nb * 16 + lr] = o[nb][i];
    if (lr == 0) {
#pragma unroll
        for (int i = 0; i < 4; i++)
            ml[w * 16 + lk * 4 + i] = l_i[i];
    }
    __syncthreads();
    for (int e = tid; e < 1024; e += 512) {
        int row = e >> 6, col = e & 63;
        float L = 0.f, O = 0.f;
#pragma unroll
        for (int ww = 0; ww < 8; ww++) {
            L += ml[ww * 16 + row];
            O += o_s[(ww * 16 + row) * 66 + col];
        }
        out[((long)b * NQ + q0 + row) * KD + col] = O / L;
    }
}

extern "C" void kernel_launch(void* const* d_in, const int* in_sizes, int n_in,
                              void* d_out, int out_size, void* d_ws, size_t ws_size,
                              hipStream_t stream) {
    const float* x      = (const float*)d_in[0];
    const float* buffer = (const float*)d_in[1];
    const int*   mask   = (const int*)d_in[2];
    const float* Wq     = (const float*)d_in[3];
    const float* bq     = (const float*)d_in[4];
    const float* Wk     = (const float*)d_in[5];
    const float* bk     = (const float*)d_in[6];
    const float* Wv     = (const float*)d_in[7];
    const float* bv     = (const float*)d_in[8];
    float* out = (float*)d_out;

    unsigned* pk = (unsigned*)d_ws;                               // 8.39 MB
    __bf16* Qb = (__bf16*)((char*)d_ws + (size_t)NB * NQ * PKW * 4);
    __bf16* Kb = Qb + (size_t)NB * NQ * KD;
    __bf16* Vt = Kb + (size_t)NB * NK * KD;

    prep_kernel<<<dim3(1024 + PACK_BLOCKS), dim3(256), 0, stream>>>(
        x, buffer, mask, Wq, bq, Wk, bk, Wv, bv, Qb, Kb, Vt, pk);
    attn_kernel<<<dim3(NB * (NQ / 16)), dim3(512), 0, stream>>>(Qb, Kb, Vt, pk, out);
}